// Round 20
// baseline (82.038 us; speedup 1.0000x reference)
//
#include <hip/hip_runtime.h>
#include <hip/hip_bf16.h>
#include <cstdint>
#include <cstddef>

#define NB 2048
#define TAU 32
#define T0C 96
#define LQ 128      // T0 + tau
#define DD 64
#define DOUT 64
#define KK 16
#define INVK 0xFFFFFFFFu

typedef unsigned int u32;
typedef __attribute__((ext_vector_type(8))) short short8;
typedef __attribute__((ext_vector_type(4))) float f32x4;

// exact-rounding helpers: keep d2 bit-identical to the reference (no fma fusion)
__device__ __forceinline__ float fmul_exact(float a, float b) {
  float r; asm("v_mul_f32 %0, %1, %2" : "=v"(r) : "v"(a), "v"(b)); return r;
}
__device__ __forceinline__ float fadd_exact(float a, float b) {
  float r; asm("v_add_f32 %0, %1, %2" : "=v"(r) : "v"(a), "v"(b)); return r;
}
__device__ __forceinline__ unsigned short f2bf(float f) {
  __hip_bfloat16 h = __float2bfloat16(f);
  return *reinterpret_cast<unsigned short*>(&h);
}
__device__ __forceinline__ u32 shfl_xor_u32(u32 v, int mask) {
  return (u32)__shfl_xor((int)v, mask, 64);
}

// lgkm-only workgroup barrier: does NOT drain vmcnt (m201-verified pattern)
__device__ __forceinline__ void barrier_lgkm() {
  asm volatile("s_waitcnt lgkmcnt(0)" ::: "memory");
  __builtin_amdgcn_s_barrier();
  __builtin_amdgcn_sched_barrier(0);
}

// u32 compare-exchange: ascending / descending
#define CA(i, j) { u32 _lo = min(kd[i], kd[j]); u32 _hi = max(kd[i], kd[j]); kd[i] = _lo; kd[j] = _hi; }
#define CD(i, j) { u32 _lo = min(kd[i], kd[j]); u32 _hi = max(kd[i], kd[j]); kd[i] = _hi; kd[j] = _lo; }

// full bitonic sort of kd[0..15], ascending (static network, 80 CAS)
#define SORT16() do { \
  CA(0,1)  CD(2,3)  CA(4,5)  CD(6,7)  CA(8,9)  CD(10,11) CA(12,13) CD(14,15) \
  CA(0,2)  CA(1,3)  CD(4,6)  CD(5,7)  CA(8,10) CA(9,11)  CD(12,14) CD(13,15) \
  CA(0,1)  CA(2,3)  CD(4,5)  CD(6,7)  CA(8,9)  CA(10,11) CD(12,13) CD(14,15) \
  CA(0,4)  CA(1,5)  CA(2,6)  CA(3,7)  CD(8,12) CD(9,13)  CD(10,14) CD(11,15) \
  CA(0,2)  CA(1,3)  CA(4,6)  CA(5,7)  CD(8,10) CD(9,11)  CD(12,14) CD(13,15) \
  CA(0,1)  CA(2,3)  CA(4,5)  CA(6,7)  CD(8,9)  CD(10,11) CD(12,13) CD(14,15) \
  CA(0,8)  CA(1,9)  CA(2,10) CA(3,11) CA(4,12) CA(5,13)  CA(6,14)  CA(7,15)  \
  CA(0,4)  CA(1,5)  CA(2,6)  CA(3,7)  CA(8,12) CA(9,13)  CA(10,14) CA(11,15) \
  CA(0,2)  CA(1,3)  CA(4,6)  CA(5,7)  CA(8,10) CA(9,11)  CA(12,14) CA(13,15) \
  CA(0,1)  CA(2,3)  CA(4,5)  CA(6,7)  CA(8,9)  CA(10,11) CA(12,13) CA(14,15) \
} while (0)

// bitonic merge of a bitonic kd[0..15] -> ascending (4 stages, 32 CAS)
#define MERGE16() do { \
  CA(0,8)  CA(1,9)  CA(2,10) CA(3,11) CA(4,12) CA(5,13)  CA(6,14)  CA(7,15)  \
  CA(0,4)  CA(1,5)  CA(2,6)  CA(3,7)  CA(8,12) CA(9,13)  CA(10,14) CA(11,15) \
  CA(0,2)  CA(1,3)  CA(4,6)  CA(5,7)  CA(8,10) CA(9,11)  CA(12,14) CA(13,15) \
  CA(0,1)  CA(2,3)  CA(4,5)  CA(6,7)  CA(8,9)  CA(10,11) CA(12,13) CA(14,15) \
} while (0)

// merge sorted kd with partner lane's sorted list (xor mask), keep lowest 16
#define SHUF_MERGE(mask) do { \
  u32 pb[16]; \
  _Pragma("unroll") \
  for (int _i = 0; _i < 16; ++_i) pb[_i] = shfl_xor_u32(kd[15 - _i], mask); \
  _Pragma("unroll") \
  for (int _i = 0; _i < 16; ++_i) kd[_i] = min(kd[_i], pb[_i]); \
  MERGE16(); \
} while (0)

// ---------- pre-kernel: bf16 transposed weights into d_ws ----------
__global__ __launch_bounds__(256) void prep_w(
    const float* __restrict__ W_nbr, const float* __restrict__ W_self,
    unsigned short* __restrict__ wst) {
  int idx = blockIdx.x * 256 + threadIdx.x;   // grid 32 -> 8192
  int m = idx & 4095;
  int n = m >> 6, k = m & 63;
  const float* src = (idx < 4096) ? W_nbr : W_self;
  wst[idx] = f2bf(src[k * DOUT + n]);
}

__global__ __launch_bounds__(256, 4) void navgcm_fused(
    const float* __restrict__ x, const float* __restrict__ pos_in, const float* __restrict__ rot_in,
    const float* __restrict__ old_x, const float* __restrict__ old_pos, const float* __restrict__ old_rot,
    const float* __restrict__ W_self, const float* __restrict__ W_nbr, const float* __restrict__ bias,
    const unsigned short* __restrict__ wst,
    float* __restrict__ outp)
{
  const int tid = threadIdx.x;
  const int lane = tid & 63;
  const int wv = tid >> 6;
  const int fr = lane & 15;   // MFMA fragment row/col within tile
  const int fg = lane >> 4;   // MFMA fragment k-group / row-group
  const int mt = wv & 1;
  const int ntb = (wv >> 1) * 2;

  // LDS 32768 B -> 4-5 blocks/CU; persistent grid 1024 = exactly 4/CU resident
  __shared__ __align__(16) unsigned short HsT[64 * 136];
  __shared__ __align__(16) unsigned short Hq[32 * 72];
  __shared__ __align__(16) unsigned short Pm[32][136];
  __shared__ float px[LQ], py[LQ], pz[LQ], rt[LQ];

  const bool haspos = tid < LQ;
  float* dpos = outp + (size_t)NB * TAU * DOUT + (size_t)NB * LQ * DD;
  float* drot = dpos + (size_t)NB * LQ * 3;
  f32x4* dnx = (f32x4*)(outp + (size_t)NB * TAU * DOUT);
  const unsigned short* wn_t = wst;            // [64][64] bf16, [n][k]
  const unsigned short* ws_t = wst + 4096;

  #pragma unroll 1
  for (int bb = 0; bb < 2; ++bb) {
    const int b = 2 * blockIdx.x + bb;
    if (bb) barrier_lgkm();   // be: prev batch's LDS reads done before overwrite

    // ====== phase A0: issue pos loads, then H loads; zero P; no vm waits ======
    float p0 = 0.f, p1 = 0.f, p2 = 0.f, rr = 0.f;
    if (haspos) {
      int t = tid;
      if (t < T0C) {
        const float* s = old_pos + ((size_t)b * LQ + t) * 3;
        p0 = s[0]; p1 = s[1]; p2 = s[2];
        rr = old_rot[(size_t)b * LQ + t];
      } else {
        const float* s = pos_in + ((size_t)b * TAU + (t - T0C)) * 3;
        p0 = s[0]; p1 = s[1]; p2 = s[2];
        rr = rot_in[(size_t)b * TAU + (t - T0C)];
      }
    }

    f32x4 v[8];
    #pragma unroll
    for (int it = 0; it < 8; ++it) {
      int n = tid + 256 * it;              // [0,2048): row = n>>4, c4 = n&15
      int row = n >> 4, c4 = n & 15;
      const f32x4* src = (row < T0C)
          ? (const f32x4*)(old_x + ((size_t)b * LQ + row) * DD)
          : (const f32x4*)(x + ((size_t)b * TAU + (row - T0C)) * DD);
      v[it] = src[c4];
    }

    // zero P incl. pad cols (32*136 u16 = 2176 u32)
    {
      u32* pz32 = (u32*)&Pm[0][0];
      #pragma unroll
      for (int k = 0; k < 9; ++k) {
        int idx2 = tid + 256 * k;
        if (idx2 < 2176) pz32[idx2] = 0u;
      }
    }

    // stage pos to LDS + emit new_pos/new_rot (non-temporal: never re-read)
    if (haspos) {
      px[tid] = p0; py[tid] = p1; pz[tid] = p2; rt[tid] = rr;
      size_t g = (size_t)b * LQ + tid;
      __builtin_nontemporal_store(p0, &dpos[g * 3 + 0]);
      __builtin_nontemporal_store(p1, &dpos[g * 3 + 1]);
      __builtin_nontemporal_store(p2, &dpos[g * 3 + 2]);
      __builtin_nontemporal_store(rr, &drot[g]);
    }
    barrier_lgkm();   // b0: pos + zeroed P ready; H loads remain in flight

    // ========== phase B: u32 top-16-set selection -> one-hot scatter + Gpos ==========
    {
      const int q = tid >> 3, s8 = tid & 7;
      const int i = T0C + q;
      const float pix = px[i], piy = py[i], piz = pz[i];

      u32 kb[16];
      #pragma unroll
      for (int c = 0; c < 16; ++c) {
        int j = 8 * c + s8;
        float dx = pix - px[j], dy = piy - py[j], dz = piz - pz[j];
        float d2 = fadd_exact(fadd_exact(fmul_exact(dx, dx), fmul_exact(dy, dy)),
                              fmul_exact(dz, dz));
        bool valid = (d2 <= 1.0f) && (j < i);
        kb[c] = valid ? __float_as_uint(d2) : INVK;
      }

      u32 kd[16];
      #pragma unroll
      for (int c = 0; c < 16; ++c) kd[c] = kb[c];
      SORT16();
      SHUF_MERGE(1);
      SHUF_MERGE(2);
      SHUF_MERGE(4);   // all 8 lanes now hold the global sorted top-16 d2bits

      const u32 T = kd[15];
      int nless = 0;
      #pragma unroll
      for (int t = 0; t < KK; ++t) nless += (kd[t] < T) ? 1 : 0;
      const int needT = (T == INVK) ? 0 : (KK - nless);

      u32 selmask = 0;
      #pragma unroll
      for (int c = 0; c < 16; ++c) selmask |= (kb[c] < T) ? (1u << c) : 0u;

      u32 em = 0;
      #pragma unroll
      for (int c = 0; c < 16; ++c) em |= (kb[c] == T) ? (1u << c) : 0u;
      if (T == INVK) em = 0;
      for (int t = 0; __any(t < needT); ++t) {
        bool act = t < needT;
        u32 myj = (act && em) ? (u32)(8 * __builtin_ctz(em) + s8) : 0xFFFFu;
        u32 gj = myj;
        gj = min(gj, shfl_xor_u32(gj, 1));
        gj = min(gj, shfl_xor_u32(gj, 2));
        gj = min(gj, shfl_xor_u32(gj, 4));
        if (act && myj == gj && myj != 0xFFFFu) {
          int c = __builtin_ctz(em);
          selmask |= 1u << c;
          em &= em - 1;
        }
      }

      u32 m = selmask;
      while (m) {
        int c = __builtin_ctz(m);
        m &= m - 1;
        Pm[q][8 * c + s8] = 0x3F80;   // bf16 1.0
      }

      float g0 = 0.f, g1 = 0.f, g2 = 0.f, g3 = 0.f;
      u32 m2 = selmask;
      while (m2) {
        int c = __builtin_ctz(m2);
        m2 &= m2 - 1;
        int j = 8 * c + s8;
        g0 += px[j]; g1 += py[j]; g2 += pz[j]; g3 += rt[j];
      }
      g0 += __shfl_xor(g0, 1, 64); g0 += __shfl_xor(g0, 2, 64); g0 += __shfl_xor(g0, 4, 64);
      g1 += __shfl_xor(g1, 1, 64); g1 += __shfl_xor(g1, 2, 64); g1 += __shfl_xor(g1, 4, 64);
      g2 += __shfl_xor(g2, 1, 64); g2 += __shfl_xor(g2, 2, 64); g2 += __shfl_xor(g2, 4, 64);
      g3 += __shfl_xor(g3, 1, 64); g3 += __shfl_xor(g3, 2, 64); g3 += __shfl_xor(g3, 4, 64);
      if (s8 == 0) {
        f32x4 gv = (f32x4){g0, g1, g2, g3};
        *reinterpret_cast<f32x4*>(&Pm[q][128]) = gv;   // pad stash (never an operand)
      }
    }

    // prefetch W B-frags (L2-hot); latency hides under A1's staging work below.
    short8 bS[2][2], wbE[2][2];
    #pragma unroll
    for (int ntl = 0; ntl < 2; ++ntl) {
      int nt = ntb + ntl;
      bS[ntl][0] = *reinterpret_cast<const short8*>(&ws_t[(nt * 16 + fr) * 64 + fg * 8]);
      bS[ntl][1] = *reinterpret_cast<const short8*>(&ws_t[(nt * 16 + fr) * 64 + 32 + fg * 8]);
      wbE[ntl][0] = *reinterpret_cast<const short8*>(&wn_t[(nt * 16 + fr) * 64 + fg * 8]);
      wbE[ntl][1] = *reinterpret_cast<const short8*>(&wn_t[(nt * 16 + fr) * 64 + 32 + fg * 8]);
    }

    // ====== phase A1: HsT/Hq to LDS + new_x stores (loads landed by now) ======
    #pragma unroll
    for (int it = 0; it < 8; ++it) {
      int n = tid + 256 * it;
      int row = n >> 4, c4 = n & 15;
      unsigned short w0 = f2bf(v[it].x), w1 = f2bf(v[it].y),
                     w2 = f2bf(v[it].z), w3 = f2bf(v[it].w);
      int rj = row ^ ((c4 & 7) << 3);   // j-swizzle: key = (nf>>2)&7 = c4&7
      HsT[(4 * c4 + 0) * 136 + rj] = w0;
      HsT[(4 * c4 + 1) * 136 + rj] = w1;
      HsT[(4 * c4 + 2) * 136 + rj] = w2;
      HsT[(4 * c4 + 3) * 136 + rj] = w3;
      if (it >= 6) {   // rows 96..127: also row-major for self-GEMM A-frags
        ushort4 w4; w4.x = w0; w4.y = w1; w4.z = w2; w4.w = w3;
        *reinterpret_cast<ushort4*>(&Hq[(row - T0C) * 72 + c4 * 4]) = w4;
      }
      __builtin_nontemporal_store(v[it], &dnx[(size_t)b * 2048 + n]);
    }
    barrier_lgkm();   // b1: HsT + Hq + Pm + Gpos ready (stores NOT drained)

    // ===== phase C: G = P @ Hx (MFMA) + self-term MFMA =====
    f32x4 accG[2];
    #pragma unroll
    for (int n = 0; n < 2; ++n) accG[n] = (f32x4){0.f, 0.f, 0.f, 0.f};
    __builtin_amdgcn_s_setprio(1);
    #pragma unroll
    for (int ks = 0; ks < 4; ++ks) {
      short8 pa = *reinterpret_cast<const short8*>(&Pm[mt * 16 + fr][ks * 32 + fg * 8]);
      #pragma unroll
      for (int ntl = 0; ntl < 2; ++ntl) {
        int nf = (ntb + ntl) * 16 + fr;
        int j0 = (ks * 32 + fg * 8) ^ (((nf >> 2) & 7) << 3);
        short8 hb = *reinterpret_cast<const short8*>(&HsT[nf * 136 + j0]);
        accG[ntl] = __builtin_amdgcn_mfma_f32_16x16x32_bf16(pa, hb, accG[ntl], 0, 0, 0);
      }
    }

    short8 aQ0 = *reinterpret_cast<const short8*>(&Hq[(mt * 16 + fr) * 72 + fg * 8]);
    short8 aQ1 = *reinterpret_cast<const short8*>(&Hq[(mt * 16 + fr) * 72 + 32 + fg * 8]);
    f32x4 acc2[2];
    #pragma unroll
    for (int n = 0; n < 2; ++n) acc2[n] = (f32x4){0.f, 0.f, 0.f, 0.f};
    #pragma unroll
    for (int ntl = 0; ntl < 2; ++ntl) {
      acc2[ntl] = __builtin_amdgcn_mfma_f32_16x16x32_bf16(aQ0, bS[ntl][0], acc2[ntl], 0, 0, 0);
      acc2[ntl] = __builtin_amdgcn_mfma_f32_16x16x32_bf16(aQ1, bS[ntl][1], acc2[ntl], 0, 0, 0);
    }
    __builtin_amdgcn_s_setprio(0);
    barrier_lgkm();   // bc: all HsT/Hq reads done -> Hq region reusable as G

    // stage G (bf16, [q][k] k-contig) into the Hq union region
    #pragma unroll
    for (int ntl = 0; ntl < 2; ++ntl) {
      int nf = (ntb + ntl) * 16 + fr;
      #pragma unroll
      for (int r = 0; r < 4; ++r) {
        int q = mt * 16 + fg * 4 + r;   // C/D: col=lane&15, row=(lane>>4)*4+r
        Hq[q * 72 + nf] = f2bf(accG[ntl][r]);
      }
    }

    // prefetch epilogue scalars (L2-hot) — latency hides under b2 + E's MFMAs
    float wn4[2][4], ws4[2][4], bi2[2];
    #pragma unroll
    for (int ntl = 0; ntl < 2; ++ntl) {
      int col = (ntb + ntl) * 16 + fr;
      wn4[ntl][0] = W_nbr[64 * DOUT + col]; wn4[ntl][1] = W_nbr[65 * DOUT + col];
      wn4[ntl][2] = W_nbr[66 * DOUT + col]; wn4[ntl][3] = W_nbr[67 * DOUT + col];
      ws4[ntl][0] = W_self[64 * DOUT + col]; ws4[ntl][1] = W_self[65 * DOUT + col];
      ws4[ntl][2] = W_self[66 * DOUT + col]; ws4[ntl][3] = W_self[67 * DOUT + col];
      bi2[ntl] = bias[col];
    }
    barrier_lgkm();   // b2: G ready

    // ====== phase E: agg = G @ Wn (MFMA) + epilogue ======
    f32x4 agg4[2];
    #pragma unroll
    for (int n = 0; n < 2; ++n) agg4[n] = (f32x4){0.f, 0.f, 0.f, 0.f};
    __builtin_amdgcn_s_setprio(1);
    #pragma unroll
    for (int ks = 0; ks < 2; ++ks) {
      short8 ga = *reinterpret_cast<const short8*>(&Hq[(mt * 16 + fr) * 72 + ks * 32 + fg * 8]);
      #pragma unroll
      for (int ntl = 0; ntl < 2; ++ntl) {
        agg4[ntl] = __builtin_amdgcn_mfma_f32_16x16x32_bf16(ga, wbE[ntl][ks], agg4[ntl], 0, 0, 0);
      }
    }
    __builtin_amdgcn_s_setprio(0);

    f32x4 gpv[4];
    #pragma unroll
    for (int r = 0; r < 4; ++r)
      gpv[r] = *reinterpret_cast<const f32x4*>(&Pm[mt * 16 + fg * 4 + r][128]);

    #pragma unroll
    for (int ntl = 0; ntl < 2; ++ntl) {
      int col = (ntb + ntl) * 16 + fr;
      #pragma unroll
      for (int r = 0; r < 4; ++r) {
        int q = mt * 16 + fg * 4 + r;
        int row = T0C + q;
        float vv = acc2[ntl][r] + agg4[ntl][r] + bi2[ntl]
                 + gpv[r].x * wn4[ntl][0] + gpv[r].y * wn4[ntl][1]
                 + gpv[r].z * wn4[ntl][2] + gpv[r].w * wn4[ntl][3]
                 + px[row] * ws4[ntl][0] + py[row] * ws4[ntl][1]
                 + pz[row] * ws4[ntl][2] + rt[row] * ws4[ntl][3];
        vv = fmaxf(vv, 0.f);
        __builtin_nontemporal_store(vv, &outp[((size_t)b * TAU + q) * DOUT + col]);
      }
    }
  }
}

extern "C" void kernel_launch(void* const* d_in, const int* in_sizes, int n_in,
                              void* d_out, int out_size, void* d_ws, size_t ws_size,
                              hipStream_t stream) {
  (void)in_sizes; (void)n_in; (void)ws_size; (void)out_size;
  const float* x       = (const float*)d_in[0];
  const float* pos     = (const float*)d_in[1];
  const float* rot     = (const float*)d_in[2];
  const float* old_x   = (const float*)d_in[3];
  const float* old_pos = (const float*)d_in[4];
  const float* old_rot = (const float*)d_in[5];
  const float* W_self  = (const float*)d_in[6];
  const float* W_nbr   = (const float*)d_in[7];
  const float* bias    = (const float*)d_in[8];
  float* out = (float*)d_out;
  unsigned short* wst = (unsigned short*)d_ws;

  hipLaunchKernelGGL(prep_w, dim3(32), dim3(256), 0, stream, W_nbr, W_self, wst);
  hipLaunchKernelGGL(navgcm_fused, dim3(NB / 2), dim3(256), 0, stream,
                     x, pos, rot, old_x, old_pos, old_rot, W_self, W_nbr, bias, wst, out);
}

// Round 21
// 37.641 us; speedup vs baseline: 2.1795x; 2.1795x over previous
//
#include <hip/hip_runtime.h>
#include <hip/hip_bf16.h>
#include <cstdint>
#include <cstddef>

#define NB 2048
#define TAU 32
#define T0C 96
#define LQ 128      // T0 + tau
#define DD 64
#define DOUT 64
#define KK 16
#define INVK 0xFFFFFFFFu

typedef unsigned int u32;
typedef __attribute__((ext_vector_type(8))) short short8;
typedef __attribute__((ext_vector_type(4))) float f32x4;

// exact-rounding helpers: keep d2 bit-identical to the reference (no fma fusion)
__device__ __forceinline__ float fmul_exact(float a, float b) {
  float r; asm("v_mul_f32 %0, %1, %2" : "=v"(r) : "v"(a), "v"(b)); return r;
}
__device__ __forceinline__ float fadd_exact(float a, float b) {
  float r; asm("v_add_f32 %0, %1, %2" : "=v"(r) : "v"(a), "v"(b)); return r;
}
__device__ __forceinline__ unsigned short f2bf(float f) {
  __hip_bfloat16 h = __float2bfloat16(f);
  return *reinterpret_cast<unsigned short*>(&h);
}
__device__ __forceinline__ u32 shfl_xor_u32(u32 v, int mask) {
  return (u32)__shfl_xor((int)v, mask, 64);
}

// lgkm-only workgroup barrier: does NOT drain vmcnt (m201-verified pattern)
__device__ __forceinline__ void barrier_lgkm() {
  asm volatile("s_waitcnt lgkmcnt(0)" ::: "memory");
  __builtin_amdgcn_s_barrier();
  __builtin_amdgcn_sched_barrier(0);
}

// u32 compare-exchange: ascending / descending
#define CA(i, j) { u32 _lo = min(kd[i], kd[j]); u32 _hi = max(kd[i], kd[j]); kd[i] = _lo; kd[j] = _hi; }
#define CD(i, j) { u32 _lo = min(kd[i], kd[j]); u32 _hi = max(kd[i], kd[j]); kd[i] = _hi; kd[j] = _lo; }

// full bitonic sort of kd[0..15], ascending (static network, 80 CAS)
#define SORT16() do { \
  CA(0,1)  CD(2,3)  CA(4,5)  CD(6,7)  CA(8,9)  CD(10,11) CA(12,13) CD(14,15) \
  CA(0,2)  CA(1,3)  CD(4,6)  CD(5,7)  CA(8,10) CA(9,11)  CD(12,14) CD(13,15) \
  CA(0,1)  CA(2,3)  CD(4,5)  CD(6,7)  CA(8,9)  CA(10,11) CD(12,13) CD(14,15) \
  CA(0,4)  CA(1,5)  CA(2,6)  CA(3,7)  CD(8,12) CD(9,13)  CD(10,14) CD(11,15) \
  CA(0,2)  CA(1,3)  CA(4,6)  CA(5,7)  CD(8,10) CD(9,11)  CD(12,14) CD(13,15) \
  CA(0,1)  CA(2,3)  CA(4,5)  CA(6,7)  CD(8,9)  CD(10,11) CD(12,13) CD(14,15) \
  CA(0,8)  CA(1,9)  CA(2,10) CA(3,11) CA(4,12) CA(5,13)  CA(6,14)  CA(7,15)  \
  CA(0,4)  CA(1,5)  CA(2,6)  CA(3,7)  CA(8,12) CA(9,13)  CA(10,14) CA(11,15) \
  CA(0,2)  CA(1,3)  CA(4,6)  CA(5,7)  CA(8,10) CA(9,11)  CA(12,14) CA(13,15) \
  CA(0,1)  CA(2,3)  CA(4,5)  CA(6,7)  CA(8,9)  CA(10,11) CA(12,13) CA(14,15) \
} while (0)

// bitonic merge of a bitonic kd[0..15] -> ascending (4 stages, 32 CAS)
#define MERGE16() do { \
  CA(0,8)  CA(1,9)  CA(2,10) CA(3,11) CA(4,12) CA(5,13)  CA(6,14)  CA(7,15)  \
  CA(0,4)  CA(1,5)  CA(2,6)  CA(3,7)  CA(8,12) CA(9,13)  CA(10,14) CA(11,15) \
  CA(0,2)  CA(1,3)  CA(4,6)  CA(5,7)  CA(8,10) CA(9,11)  CA(12,14) CA(13,15) \
  CA(0,1)  CA(2,3)  CA(4,5)  CA(6,7)  CA(8,9)  CA(10,11) CA(12,13) CA(14,15) \
} while (0)

// merge sorted kd with partner lane's sorted list (xor mask), keep lowest 16
#define SHUF_MERGE(mask) do { \
  u32 pb[16]; \
  _Pragma("unroll") \
  for (int _i = 0; _i < 16; ++_i) pb[_i] = shfl_xor_u32(kd[15 - _i], mask); \
  _Pragma("unroll") \
  for (int _i = 0; _i < 16; ++_i) kd[_i] = min(kd[_i], pb[_i]); \
  MERGE16(); \
} while (0)

// ---------- pre-kernel: bf16 transposed weights into d_ws ----------
__global__ __launch_bounds__(256) void prep_w(
    const float* __restrict__ W_nbr, const float* __restrict__ W_self,
    unsigned short* __restrict__ wst) {
  int idx = blockIdx.x * 256 + threadIdx.x;   // grid 32 -> 8192
  int m = idx & 4095;
  int n = m >> 6, k = m & 63;
  const float* src = (idx < 4096) ? W_nbr : W_self;
  wst[idx] = f2bf(src[k * DOUT + n]);
}

__global__ __launch_bounds__(256, 4) void navgcm_fused(
    const float* __restrict__ x, const float* __restrict__ pos_in, const float* __restrict__ rot_in,
    const float* __restrict__ old_x, const float* __restrict__ old_pos, const float* __restrict__ old_rot,
    const float* __restrict__ W_self, const float* __restrict__ W_nbr, const float* __restrict__ bias,
    const unsigned short* __restrict__ wst,
    float* __restrict__ outp)
{
  const int b = blockIdx.x;
  const int tid = threadIdx.x;
  const int lane = tid & 63;
  const int wv = tid >> 6;
  const int fr = lane & 15;   // MFMA fragment row/col within tile
  const int fg = lane >> 4;   // MFMA fragment k-group / row-group
  const int mt = wv & 1;
  const int ntb = (wv >> 1) * 2;

  // LDS 32768 B -> 5 blocks/CU (LDS-limited; VGPR ~56 allows more):
  //   HsT 64x136 u16 | Hq/G union 32x72 u16 | Pm 32x136 u16 (pad cols = Gpos) | pos
  __shared__ __align__(16) unsigned short HsT[64 * 136];
  __shared__ __align__(16) unsigned short Hq[32 * 72];
  __shared__ __align__(16) unsigned short Pm[32][136];
  __shared__ float px[LQ], py[LQ], pz[LQ], rt[LQ];

  // ====== phase A0: issue pos loads, then H loads; zero P; no vm waits ======
  const bool haspos = tid < LQ;
  float p0 = 0.f, p1 = 0.f, p2 = 0.f, rr = 0.f;
  if (haspos) {
    int t = tid;
    if (t < T0C) {
      const float* s = old_pos + ((size_t)b * LQ + t) * 3;
      p0 = s[0]; p1 = s[1]; p2 = s[2];
      rr = old_rot[(size_t)b * LQ + t];
    } else {
      const float* s = pos_in + ((size_t)b * TAU + (t - T0C)) * 3;
      p0 = s[0]; p1 = s[1]; p2 = s[2];
      rr = rot_in[(size_t)b * TAU + (t - T0C)];
    }
  }

  f32x4 v[8];
  #pragma unroll
  for (int it = 0; it < 8; ++it) {
    int n = tid + 256 * it;              // [0,2048): row = n>>4, c4 = n&15
    int row = n >> 4, c4 = n & 15;
    const f32x4* src = (row < T0C)
        ? (const f32x4*)(old_x + ((size_t)b * LQ + row) * DD)
        : (const f32x4*)(x + ((size_t)b * TAU + (row - T0C)) * DD);
    v[it] = src[c4];
  }

  // zero P incl. pad cols (32*136 u16 = 2176 u32)
  {
    u32* pz32 = (u32*)&Pm[0][0];
    #pragma unroll
    for (int k = 0; k < 9; ++k) {
      int idx2 = tid + 256 * k;
      if (idx2 < 2176) pz32[idx2] = 0u;
    }
  }

  // stage pos to LDS + emit new_pos/new_rot (non-temporal: never re-read)
  float* dpos = outp + (size_t)NB * TAU * DOUT + (size_t)NB * LQ * DD;
  float* drot = dpos + (size_t)NB * LQ * 3;
  if (haspos) {
    px[tid] = p0; py[tid] = p1; pz[tid] = p2; rt[tid] = rr;
    size_t g = (size_t)b * LQ + tid;
    __builtin_nontemporal_store(p0, &dpos[g * 3 + 0]);
    __builtin_nontemporal_store(p1, &dpos[g * 3 + 1]);
    __builtin_nontemporal_store(p2, &dpos[g * 3 + 2]);
    __builtin_nontemporal_store(rr, &drot[g]);
  }
  barrier_lgkm();   // b0: pos + zeroed P ready; H loads remain in flight

  // ========== phase B: u32 top-16-set selection -> one-hot scatter + Gpos ==========
  {
    const int q = tid >> 3, s8 = tid & 7;
    const int i = T0C + q;
    const float pix = px[i], piy = py[i], piz = pz[i];

    // per-candidate keys (d2 bits; INVK if invalid). j = 8c + s8.
    u32 kb[16];
    #pragma unroll
    for (int c = 0; c < 16; ++c) {
      int j = 8 * c + s8;
      float dx = pix - px[j], dy = piy - py[j], dz = piz - pz[j];
      float d2 = fadd_exact(fadd_exact(fmul_exact(dx, dx), fmul_exact(dy, dy)),
                            fmul_exact(dz, dz));
      bool valid = (d2 <= 1.0f) && (j < i);
      kb[c] = valid ? __float_as_uint(d2) : INVK;
    }

    // sorted working copy + 3-level min-merge across the 8 lanes of this query
    u32 kd[16];
    #pragma unroll
    for (int c = 0; c < 16; ++c) kd[c] = kb[c];
    SORT16();
    SHUF_MERGE(1);
    SHUF_MERGE(2);
    SHUF_MERGE(4);   // all 8 lanes now hold the global sorted top-16 d2bits

    const u32 T = kd[15];
    int nless = 0;
    #pragma unroll
    for (int t = 0; t < KK; ++t) nless += (kd[t] < T) ? 1 : 0;
    const int needT = (T == INVK) ? 0 : (KK - nless);

    // selection mask over own candidates: all < T
    u32 selmask = 0;
    #pragma unroll
    for (int c = 0; c < 16; ++c) selmask |= (kb[c] < T) ? (1u << c) : 0u;

    // ties at T: pick the needT smallest j (ascending j == lax.top_k stable rule)
    u32 em = 0;
    #pragma unroll
    for (int c = 0; c < 16; ++c) em |= (kb[c] == T) ? (1u << c) : 0u;
    if (T == INVK) em = 0;
    for (int t = 0; __any(t < needT); ++t) {
      bool act = t < needT;
      u32 myj = (act && em) ? (u32)(8 * __builtin_ctz(em) + s8) : 0xFFFFu;
      u32 gj = myj;
      gj = min(gj, shfl_xor_u32(gj, 1));
      gj = min(gj, shfl_xor_u32(gj, 2));
      gj = min(gj, shfl_xor_u32(gj, 4));
      if (act && myj == gj && myj != 0xFFFFu) {
        int c = __builtin_ctz(em);
        selmask |= 1u << c;
        em &= em - 1;
      }
    }

    // scatter one-hot: P[q][j] = 1.0bf16 for each selected j (j=8c+s8)
    u32 m = selmask;
    while (m) {
      int c = __builtin_ctz(m);
      m &= m - 1;
      Pm[q][8 * c + s8] = 0x3F80;   // bf16 1.0
    }

    // Gpos: f32 sums of selected pos/rot -> stashed in Pm pad cols [128..135]
    float g0 = 0.f, g1 = 0.f, g2 = 0.f, g3 = 0.f;
    u32 m2 = selmask;
    while (m2) {
      int c = __builtin_ctz(m2);
      m2 &= m2 - 1;
      int j = 8 * c + s8;
      g0 += px[j]; g1 += py[j]; g2 += pz[j]; g3 += rt[j];
    }
    g0 += __shfl_xor(g0, 1, 64); g0 += __shfl_xor(g0, 2, 64); g0 += __shfl_xor(g0, 4, 64);
    g1 += __shfl_xor(g1, 1, 64); g1 += __shfl_xor(g1, 2, 64); g1 += __shfl_xor(g1, 4, 64);
    g2 += __shfl_xor(g2, 1, 64); g2 += __shfl_xor(g2, 2, 64); g2 += __shfl_xor(g2, 4, 64);
    g3 += __shfl_xor(g3, 1, 64); g3 += __shfl_xor(g3, 2, 64); g3 += __shfl_xor(g3, 4, 64);
    if (s8 == 0) {
      f32x4 gv = (f32x4){g0, g1, g2, g3};
      *reinterpret_cast<f32x4*>(&Pm[q][128]) = gv;   // pad stash (never read as operand)
    }
  }

  // prefetch W B-frags (L2-hot) now that selection temps are dead; their
  // latency hides under A1's staging work below.
  const unsigned short* wn_t = wst;            // [64][64] bf16, [n][k]
  const unsigned short* ws_t = wst + 4096;
  short8 bS[2][2], wbE[2][2];
  #pragma unroll
  for (int ntl = 0; ntl < 2; ++ntl) {
    int nt = ntb + ntl;
    bS[ntl][0] = *reinterpret_cast<const short8*>(&ws_t[(nt * 16 + fr) * 64 + fg * 8]);
    bS[ntl][1] = *reinterpret_cast<const short8*>(&ws_t[(nt * 16 + fr) * 64 + 32 + fg * 8]);
    wbE[ntl][0] = *reinterpret_cast<const short8*>(&wn_t[(nt * 16 + fr) * 64 + fg * 8]);
    wbE[ntl][1] = *reinterpret_cast<const short8*>(&wn_t[(nt * 16 + fr) * 64 + 32 + fg * 8]);
  }

  // ====== phase A1: HsT/Hq to LDS + new_x stores (loads landed by now) ======
  f32x4* dnx = (f32x4*)(outp + (size_t)NB * TAU * DOUT);
  #pragma unroll
  for (int it = 0; it < 8; ++it) {
    int n = tid + 256 * it;
    int row = n >> 4, c4 = n & 15;
    unsigned short w0 = f2bf(v[it].x), w1 = f2bf(v[it].y),
                   w2 = f2bf(v[it].z), w3 = f2bf(v[it].w);
    // transposed stage with j-swizzle: feature nf = 4*c4 + c; key = (nf>>2)&7 = c4&7
    int rj = row ^ ((c4 & 7) << 3);
    HsT[(4 * c4 + 0) * 136 + rj] = w0;
    HsT[(4 * c4 + 1) * 136 + rj] = w1;
    HsT[(4 * c4 + 2) * 136 + rj] = w2;
    HsT[(4 * c4 + 3) * 136 + rj] = w3;
    if (it >= 6) {   // rows 96..127: also row-major for self-GEMM A-frags
      ushort4 w4; w4.x = w0; w4.y = w1; w4.z = w2; w4.w = w3;
      *reinterpret_cast<ushort4*>(&Hq[(row - T0C) * 72 + c4 * 4]) = w4;
    }
    __builtin_nontemporal_store(v[it], &dnx[(size_t)b * 2048 + n]);
  }
  barrier_lgkm();   // b1: HsT + Hq + Pm + Gpos ready (stores NOT drained)

  // ===== phase C: G = P @ Hx (MFMA) + self-term MFMA =====
  f32x4 accG[2];
  #pragma unroll
  for (int n = 0; n < 2; ++n) accG[n] = (f32x4){0.f, 0.f, 0.f, 0.f};
  __builtin_amdgcn_s_setprio(1);
  #pragma unroll
  for (int ks = 0; ks < 4; ++ks) {
    short8 pa = *reinterpret_cast<const short8*>(&Pm[mt * 16 + fr][ks * 32 + fg * 8]);
    #pragma unroll
    for (int ntl = 0; ntl < 2; ++ntl) {
      int nf = (ntb + ntl) * 16 + fr;
      int j0 = (ks * 32 + fg * 8) ^ (((nf >> 2) & 7) << 3);
      short8 hb = *reinterpret_cast<const short8*>(&HsT[nf * 136 + j0]);
      accG[ntl] = __builtin_amdgcn_mfma_f32_16x16x32_bf16(pa, hb, accG[ntl], 0, 0, 0);
    }
  }

  // self-term MFMA (registers only)
  short8 aQ0 = *reinterpret_cast<const short8*>(&Hq[(mt * 16 + fr) * 72 + fg * 8]);
  short8 aQ1 = *reinterpret_cast<const short8*>(&Hq[(mt * 16 + fr) * 72 + 32 + fg * 8]);
  f32x4 acc2[2];
  #pragma unroll
  for (int n = 0; n < 2; ++n) acc2[n] = (f32x4){0.f, 0.f, 0.f, 0.f};
  #pragma unroll
  for (int ntl = 0; ntl < 2; ++ntl) {
    acc2[ntl] = __builtin_amdgcn_mfma_f32_16x16x32_bf16(aQ0, bS[ntl][0], acc2[ntl], 0, 0, 0);
    acc2[ntl] = __builtin_amdgcn_mfma_f32_16x16x32_bf16(aQ1, bS[ntl][1], acc2[ntl], 0, 0, 0);
  }
  __builtin_amdgcn_s_setprio(0);
  barrier_lgkm();   // bc: all HsT/Hq reads done -> Hq region reusable as G

  // stage G (bf16, [q][k] k-contig) into the Hq union region
  #pragma unroll
  for (int ntl = 0; ntl < 2; ++ntl) {
    int nf = (ntb + ntl) * 16 + fr;
    #pragma unroll
    for (int r = 0; r < 4; ++r) {
      int q = mt * 16 + fg * 4 + r;   // C/D layout: col=lane&15, row=(lane>>4)*4+r
      Hq[q * 72 + nf] = f2bf(accG[ntl][r]);
    }
  }

  // prefetch epilogue scalars (L2-hot) — latency hides under b2 + E's MFMAs
  float wn4[2][4], ws4[2][4], bi2[2];
  #pragma unroll
  for (int ntl = 0; ntl < 2; ++ntl) {
    int col = (ntb + ntl) * 16 + fr;
    wn4[ntl][0] = W_nbr[64 * DOUT + col]; wn4[ntl][1] = W_nbr[65 * DOUT + col];
    wn4[ntl][2] = W_nbr[66 * DOUT + col]; wn4[ntl][3] = W_nbr[67 * DOUT + col];
    ws4[ntl][0] = W_self[64 * DOUT + col]; ws4[ntl][1] = W_self[65 * DOUT + col];
    ws4[ntl][2] = W_self[66 * DOUT + col]; ws4[ntl][3] = W_self[67 * DOUT + col];
    bi2[ntl] = bias[col];
  }
  barrier_lgkm();   // b2: G ready

  // ====== phase E: agg = G @ Wn (MFMA) + epilogue ======
  f32x4 agg4[2];
  #pragma unroll
  for (int n = 0; n < 2; ++n) agg4[n] = (f32x4){0.f, 0.f, 0.f, 0.f};
  __builtin_amdgcn_s_setprio(1);
  #pragma unroll
  for (int ks = 0; ks < 2; ++ks) {
    short8 ga = *reinterpret_cast<const short8*>(&Hq[(mt * 16 + fr) * 72 + ks * 32 + fg * 8]);
    #pragma unroll
    for (int ntl = 0; ntl < 2; ++ntl) {
      agg4[ntl] = __builtin_amdgcn_mfma_f32_16x16x32_bf16(ga, wbE[ntl][ks], agg4[ntl], 0, 0, 0);
    }
  }
  __builtin_amdgcn_s_setprio(0);

  f32x4 gpv[4];
  #pragma unroll
  for (int r = 0; r < 4; ++r)
    gpv[r] = *reinterpret_cast<const f32x4*>(&Pm[mt * 16 + fg * 4 + r][128]);

  #pragma unroll
  for (int ntl = 0; ntl < 2; ++ntl) {
    int col = (ntb + ntl) * 16 + fr;
    #pragma unroll
    for (int r = 0; r < 4; ++r) {
      int q = mt * 16 + fg * 4 + r;
      int row = T0C + q;
      float vv = acc2[ntl][r] + agg4[ntl][r] + bi2[ntl]
               + gpv[r].x * wn4[ntl][0] + gpv[r].y * wn4[ntl][1]
               + gpv[r].z * wn4[ntl][2] + gpv[r].w * wn4[ntl][3]
               + px[row] * ws4[ntl][0] + py[row] * ws4[ntl][1]
               + pz[row] * ws4[ntl][2] + rt[row] * ws4[ntl][3];
      vv = fmaxf(vv, 0.f);
      __builtin_nontemporal_store(vv, &outp[((size_t)b * TAU + q) * DOUT + col]);
    }
  }
}

extern "C" void kernel_launch(void* const* d_in, const int* in_sizes, int n_in,
                              void* d_out, int out_size, void* d_ws, size_t ws_size,
                              hipStream_t stream) {
  (void)in_sizes; (void)n_in; (void)ws_size; (void)out_size;
  const float* x       = (const float*)d_in[0];
  const float* pos     = (const float*)d_in[1];
  const float* rot     = (const float*)d_in[2];
  const float* old_x   = (const float*)d_in[3];
  const float* old_pos = (const float*)d_in[4];
  const float* old_rot = (const float*)d_in[5];
  const float* W_self  = (const float*)d_in[6];
  const float* W_nbr   = (const float*)d_in[7];
  const float* bias    = (const float*)d_in[8];
  float* out = (float*)d_out;
  unsigned short* wst = (unsigned short*)d_ws;

  hipLaunchKernelGGL(prep_w, dim3(32), dim3(256), 0, stream, W_nbr, W_self, wst);
  hipLaunchKernelGGL(navgcm_fused, dim3(NB), dim3(256), 0, stream,
                     x, pos, rot, old_x, old_pos, old_rot, W_self, W_nbr, bias, wst, out);
}